// Round 2
// baseline (1670.618 us; speedup 1.0000x reference)
//
#include <hip/hip_runtime.h>
#include <cstdint>
#include <cstddef>

#define HH 128
#define WW 128
#define LL 16384   // HH*WW
#define BL 32768   // B*LL

typedef float  f32x4  __attribute__((ext_vector_type(4)));
typedef short  bf16x8 __attribute__((ext_vector_type(8)));
typedef unsigned short u16x8 __attribute__((ext_vector_type(8)));

static __device__ __forceinline__ unsigned short f2bf(float x) {
  union { float f; unsigned int u; } c; c.f = x;
  unsigned int r = (c.u + 0x7fffu + ((c.u >> 16) & 1u)) >> 16;   // RNE
  return (unsigned short)r;
}
static __device__ __forceinline__ float bflo(unsigned int u) {
  union { unsigned int u; float f; } c; c.u = u << 16; return c.f;
}
static __device__ __forceinline__ float bfhi(unsigned int u) {
  union { unsigned int u; float f; } c; c.u = u & 0xffff0000u; return c.f;
}

// ------------- k0: fold proj into fusion weight; emit B^T bf16 [64][800], kk = t*32+c -
__global__ __launch_bounds__(256) void k_combine(
    const float* __restrict__ proj_w, const float* __restrict__ proj_b,
    const float* __restrict__ fw, const float* __restrict__ fb,
    unsigned short* __restrict__ wctT, float* __restrict__ bc)
{
  if (blockIdx.x == 200) {
    int o = threadIdx.x;
    if (o < 64) {
      float acc = proj_b[o];
      for (int m = 0; m < 64; ++m) acc = fmaf(proj_w[o*64+m], fb[m], acc);
      bc[o] = acc;
    }
    return;
  }
  int gid = blockIdx.x * 256 + threadIdx.x;   // 0..51199 = o*800 + kk
  int o  = gid / 800;
  int kk = gid - o * 800;
  int c  = kk & 31;        // de-interleaved channel (nh*16+d)
  int t  = kk >> 5;        // window position 0..24
  int in = c * 25 + t;     // fusion weight flat index
  float acc = 0.f;
  for (int m = 0; m < 64; ++m) acc = fmaf(proj_w[o*64+m], fw[m*800+in], acc);
  wctT[gid] = f2bf(acc);
}

// ---------------- k1: LayerNorm + QKV, store q/k/v de-interleaved (c' = nh*16 + d) ----
__global__ __launch_bounds__(256) void k_ln_qkv(
    const float* __restrict__ x, const float* __restrict__ qkv_w,
    const float* __restrict__ qkv_b, const float* __restrict__ n1w,
    const float* __restrict__ n1b, float* __restrict__ qo,
    float* __restrict__ ko, float* __restrict__ vo)
{
  __shared__ float sW[96*32];
  __shared__ float sB[96];
  __shared__ float sNw[32], sNb[32];
  for (int i = threadIdx.x; i < 96*32; i += 256) sW[i] = qkv_w[i];
  if (threadIdx.x < 96) sB[threadIdx.x] = qkv_b[threadIdx.x];
  if (threadIdx.x < 32) { sNw[threadIdx.x] = n1w[threadIdx.x]; sNb[threadIdx.x] = n1b[threadIdx.x]; }
  __syncthreads();
  int gid = blockIdx.x * 256 + threadIdx.x;   // 0..BL-1
  int b = gid >> 14, l = gid & (LL - 1);
  const float* xp = x + (size_t)b * 32 * LL + l;
  float xv[32];
  float mean = 0.f;
  #pragma unroll
  for (int c = 0; c < 32; ++c) { xv[c] = xp[(size_t)c * LL]; mean += xv[c]; }
  mean *= 0.03125f;
  float var = 0.f;
  #pragma unroll
  for (int c = 0; c < 32; ++c) { float d = xv[c] - mean; var = fmaf(d, d, var); }
  float rs = rsqrtf(var * 0.03125f + 1e-5f);
  #pragma unroll
  for (int c = 0; c < 32; ++c) xv[c] = (xv[c] - mean) * rs * sNw[c] + sNb[c];
  size_t base = (size_t)gid * 32;
  float* outs[3] = {qo, ko, vo};
  #pragma unroll
  for (int p = 0; p < 3; ++p) {
    float* op = outs[p] + base;
    for (int o = 0; o < 32; ++o) {
      const float* wr = &sW[(p*32 + o) * 32];
      float acc = sB[p*32 + o];
      #pragma unroll
      for (int c = 0; c < 32; ++c) acc = fmaf(xv[c], wr[c], acc);
      op[(o & 1) * 16 + (o >> 1)] = acc;
    }
  }
}

// ---------------- k2: tiled windowed attention + fused (fusion∘proj) MFMA GEMM -------
// Block = 4x8 = 32 locations, 256 threads (4 waves).
#define TH 4
#define TW 8
#define HP 8     // TH+4
#define WP 12    // TW+4
#define NPOS 96  // HP*WP
#define PSTR 36  // fp32 halo row stride (floats)
#define VSTR 40  // bf16 V halo row stride (ushorts)
#define OSTRU 264 // sO row stride (ushorts): 256 kk + 8 pad

__global__ __launch_bounds__(256, 3) void k_attn(
    const float* __restrict__ qi, const float* __restrict__ ki,
    const float* __restrict__ vi, const float* __restrict__ rel_table,
    const unsigned short* __restrict__ wctT, const float* __restrict__ bc,
    float* __restrict__ y2)
{
  __shared__ __align__(16) float sQ[NPOS*PSTR];        // 13824 B
  __shared__ __align__(16) float sK[NPOS*PSTR];        // 13824 B
  __shared__ __align__(16) unsigned short sV[NPOS*VSTR]; // 7680 B
  __shared__ __align__(16) unsigned short sO[32*OSTRU];  // 16896 B
  __shared__ float sRT[162];
  __shared__ float sPar[NPOS];

  int tid = threadIdx.x;
  int lane = tid & 63, wv = tid >> 6;
  int b  = blockIdx.z;
  int h0 = blockIdx.y * TH, w0 = blockIdx.x * TW;

  for (int i = tid; i < 162; i += 256) sRT[i] = rel_table[i];
  // halo staging: Q,K fp32; V bf16; parity flags
  for (int idx = tid; idx < NPOS*8; idx += 256) {
    int pos = idx >> 3, c4 = idx & 7;
    int ph = pos / 12, pw = pos - ph * 12;
    int h2 = h0 + ph - 2, w2 = w0 + pw - 2;
    float4 qv = make_float4(0.f,0.f,0.f,0.f), kv = qv, vv = qv;
    bool valid = ((unsigned)h2 < HH) && ((unsigned)w2 < WW);
    if (valid) {
      size_t off = ((size_t)((b << 14) + (h2 << 7) + w2)) * 32 + c4 * 4;
      qv = *(const float4*)(qi + off);
      kv = *(const float4*)(ki + off);
      vv = *(const float4*)(vi + off);
    }
    *(float4*)&sQ[pos*PSTR + c4*4] = qv;
    *(float4*)&sK[pos*PSTR + c4*4] = kv;
    uint2 vp;
    vp.x = (unsigned int)f2bf(vv.x) | ((unsigned int)f2bf(vv.y) << 16);
    vp.y = (unsigned int)f2bf(vv.z) | ((unsigned int)f2bf(vv.w) << 16);
    *(uint2*)&sV[pos*VSTR + c4*4] = vp;
    if (c4 == 0) sPar[pos] = (valid && (((h2 + w2) & 1) == 1)) ? 1.f : 0.f;
  }
  __syncthreads();

  f32x4 acc[2] = {{0.f,0.f,0.f,0.f},{0.f,0.f,0.f,0.f}};
  int ocol = wv * 16 + (lane & 15);

  for (int it = 0; it < 4; ++it) {
    int rest = it * 8 + wv * 2 + (lane >> 5);   // half-wave uniform
    if (rest < 26) {
      int nh = rest & 1, r = rest >> 1;         // r 0..12
      int tq0 = 2 * r;
      bool two = (tq0 + 1) < 25;                // wave-uniform
      int tq1 = two ? tq0 + 1 : tq0;
      int loc = lane & 31;
      int ly = loc >> 3, lx = loc & 7;
      int iq0 = tq0 / 5, jq0 = tq0 - iq0 * 5;
      int iq1 = tq1 / 5, jq1 = tq1 - iq1 * 5;
      int pq0 = (ly + iq0) * 12 + lx + jq0;
      int pq1 = (ly + iq1) * 12 + lx + jq1;
      float parq0 = sPar[pq0], parq1 = sPar[pq1];
      // q rows (window positions tq0, tq1)
      float qa[16], qb[16];
      {
        const float* p0 = &sQ[pq0*PSTR + nh*16];
        const float* p1 = &sQ[pq1*PSTR + nh*16];
        #pragma unroll
        for (int e = 0; e < 4; ++e) {
          float4 t0 = *(const float4*)(p0 + e*4);
          float4 t1 = *(const float4*)(p1 + e*4);
          qa[4*e]=t0.x; qa[4*e+1]=t0.y; qa[4*e+2]=t0.z; qa[4*e+3]=t0.w;
          qb[4*e]=t1.x; qb[4*e+1]=t1.y; qb[4*e+2]=t1.z; qb[4*e+3]=t1.w;
        }
      }
      float s0[25], s1[25];
      float mx0 = -1e30f, mx1 = -1e30f;
      #pragma unroll
      for (int tk = 0; tk < 25; ++tk) {
        const int ik = tk / 5, jk = tk % 5;     // compile-time
        int pk = (ly + ik) * 12 + lx + jk;
        const float* kp = &sK[pk*PSTR + nh*16];
        float a0 = 0.f, a1 = 0.f;
        #pragma unroll
        for (int e = 0; e < 4; ++e) {
          float4 k4 = *(const float4*)(kp + e*4);
          a0 = fmaf(qa[4*e],k4.x,a0); a0 = fmaf(qa[4*e+1],k4.y,a0);
          a0 = fmaf(qa[4*e+2],k4.z,a0); a0 = fmaf(qa[4*e+3],k4.w,a0);
          a1 = fmaf(qb[4*e],k4.x,a1); a1 = fmaf(qb[4*e+1],k4.y,a1);
          a1 = fmaf(qb[4*e+2],k4.z,a1); a1 = fmaf(qb[4*e+3],k4.w,a1);
        }
        float park = sPar[pk];
        float b0 = sRT[((iq0-ik+4)*9 + (jq0-jk+4))*2 + nh];
        float b1 = sRT[((iq1-ik+4)*9 + (jq1-jk+4))*2 + nh];
        float m0 = (parq0*park == 1.f) ? 0.f : -100.f;
        float m1 = (parq1*park == 1.f) ? 0.f : -100.f;
        s0[tk] = fmaf(a0, 0.25f, b0) + m0; mx0 = fmaxf(mx0, s0[tk]);
        s1[tk] = fmaf(a1, 0.25f, b1) + m1; mx1 = fmaxf(mx1, s1[tk]);
      }
      float sum0 = 0.f, sum1 = 0.f;
      #pragma unroll
      for (int tk = 0; tk < 25; ++tk) {
        float e0 = __expf(s0[tk]-mx0); s0[tk] = e0; sum0 += e0;
        float e1 = __expf(s1[tk]-mx1); s1[tk] = e1; sum1 += e1;
      }
      float inv0 = 1.f / sum0, inv1 = 1.f / sum1;
      #pragma unroll
      for (int tk = 0; tk < 25; ++tk) { s0[tk] *= inv0; s1[tk] *= inv1; }
      // PV (V in bf16, bit-expand)
      float o0[16], o1[16];
      #pragma unroll
      for (int d = 0; d < 16; ++d) { o0[d] = 0.f; o1[d] = 0.f; }
      #pragma unroll
      for (int tk = 0; tk < 25; ++tk) {
        const int ik = tk / 5, jk = tk % 5;
        int pk = (ly + ik) * 12 + lx + jk;
        const unsigned short* vp = &sV[pk*VSTR + nh*16];
        uint4 va = *(const uint4*)(vp);
        uint4 vb = *(const uint4*)(vp + 8);
        float p0 = s0[tk], p1 = s1[tk];
        unsigned int uu[8] = {va.x, va.y, va.z, va.w, vb.x, vb.y, vb.z, vb.w};
        #pragma unroll
        for (int u = 0; u < 8; ++u) {
          float flo = bflo(uu[u]), fhi = bfhi(uu[u]);
          o0[2*u]   = fmaf(p0, flo, o0[2*u]);
          o0[2*u+1] = fmaf(p0, fhi, o0[2*u+1]);
          o1[2*u]   = fmaf(p1, flo, o1[2*u]);
          o1[2*u+1] = fmaf(p1, fhi, o1[2*u+1]);
        }
      }
      // write O rows to sO (bf16), kk_local = (tq - it*8)*32 + nh*16
      {
        int kl0 = (tq0 - it*8) * 32 + nh * 16;
        u16x8 w0v, w1v;
        #pragma unroll
        for (int j = 0; j < 8; ++j) { w0v[j] = f2bf(o0[j]); w1v[j] = f2bf(o0[8+j]); }
        *(u16x8*)&sO[loc*OSTRU + kl0] = w0v;
        *(u16x8*)&sO[loc*OSTRU + kl0 + 8] = w1v;
        if (two) {
          int kl1 = (tq1 - it*8) * 32 + nh * 16;
          #pragma unroll
          for (int j = 0; j < 8; ++j) { w0v[j] = f2bf(o1[j]); w1v[j] = f2bf(o1[8+j]); }
          *(u16x8*)&sO[loc*OSTRU + kl1] = w0v;
          *(u16x8*)&sO[loc*OSTRU + kl1 + 8] = w1v;
        }
      }
    }
    __syncthreads();
    // MFMA phase: K-chunk [it*256, it*256 + nk*32)
    int nk = (it < 3) ? 8 : 1;
    const unsigned short* bcol = wctT + (size_t)ocol * 800 + it * 256 + (lane >> 4) * 8;
    for (int kt = 0; kt < nk; ++kt) {
      bf16x8 bfrag = *(const bf16x8*)(bcol + kt * 32);
      #pragma unroll
      for (int mt = 0; mt < 2; ++mt) {
        bf16x8 afrag = *(const bf16x8*)&sO[(mt*16 + (lane & 15))*OSTRU + kt*32 + (lane >> 4)*8];
        acc[mt] = __builtin_amdgcn_mfma_f32_16x16x32_bf16(afrag, bfrag, acc[mt], 0, 0, 0);
      }
    }
    __syncthreads();
  }
  // epilogue: y2[loc][o] = acc + bc[o]
  float bco = bc[ocol];
  #pragma unroll
  for (int mt = 0; mt < 2; ++mt) {
    #pragma unroll
    for (int r2 = 0; r2 < 4; ++r2) {
      int loc = mt * 16 + (lane >> 4) * 4 + r2;
      int ly = loc >> 3, lx = loc & 7;
      int gid = (b << 14) + ((h0 + ly) << 7) + (w0 + lx);
      y2[(size_t)gid * 64 + ocol] = acc[mt][r2] + bco;
    }
  }
}

// ---------------- k3: LN + MLP(GELU exact) + residual + transpose store --------------
__global__ __launch_bounds__(128, 1) void k_mlp(
    const float* __restrict__ y2, const float* __restrict__ n2w,
    const float* __restrict__ n2b, const float* __restrict__ w1,
    const float* __restrict__ b1, const float* __restrict__ w2,
    const float* __restrict__ b2, float* __restrict__ out)
{
  __shared__ __align__(16) float sW1[128*64];
  __shared__ __align__(16) float sW2[64*128];
  __shared__ float sNw[64], sNb[64], sB1[128], sB2[64];
  int tid = threadIdx.x;
  for (int i = tid; i < 128*64; i += 128) sW1[i] = w1[i];
  for (int i = tid; i < 64*128; i += 128) sW2[i] = w2[i];
  if (tid < 64) { sNw[tid] = n2w[tid]; sNb[tid] = n2b[tid]; sB2[tid] = b2[tid]; }
  sB1[tid] = b1[tid];
  __syncthreads();
  int gid = blockIdx.x * 128 + tid;
  int b = gid >> 14, l = gid & (LL - 1);
  float yv[64], hn[64], macc[64];
  const float* yp = y2 + (size_t)gid * 64;
  float mean = 0.f;
  #pragma unroll
  for (int c = 0; c < 64; ++c) { yv[c] = yp[c]; mean += yv[c]; }
  mean *= (1.f/64.f);
  float var = 0.f;
  #pragma unroll
  for (int c = 0; c < 64; ++c) { float d = yv[c] - mean; var = fmaf(d, d, var); }
  float rs = rsqrtf(var * (1.f/64.f) + 1e-5f);
  #pragma unroll
  for (int c = 0; c < 64; ++c) hn[c] = (yv[c] - mean) * rs * sNw[c] + sNb[c];
  #pragma unroll
  for (int o = 0; o < 64; ++o) macc[o] = sB2[o];
  for (int j4 = 0; j4 < 32; ++j4) {
    float g[4];
    #pragma unroll
    for (int u = 0; u < 4; ++u) {
      int j = j4*4 + u;
      const float* wr = &sW1[j*64];
      float hj = sB1[j];
      #pragma unroll
      for (int c = 0; c < 64; ++c) hj = fmaf(hn[c], wr[c], hj);
      g[u] = 0.5f * hj * (1.f + erff(hj * 0.70710678118f));
    }
    #pragma unroll
    for (int o = 0; o < 64; ++o) {
      const float4 w4 = *(const float4*)(&sW2[o*128 + j4*4]);
      macc[o] = fmaf(g[0], w4.x, fmaf(g[1], w4.y, fmaf(g[2], w4.z, fmaf(g[3], w4.w, macc[o]))));
    }
  }
  size_t ob = (size_t)b * 64 * LL + l;
  #pragma unroll
  for (int o = 0; o < 64; ++o) out[ob + (size_t)o * LL] = yv[o] + macc[o];
}

extern "C" void kernel_launch(void* const* d_in, const int* in_sizes, int n_in,
                              void* d_out, int out_size, void* d_ws, size_t ws_size,
                              hipStream_t stream) {
  const float* x         = (const float*)d_in[0];
  const float* qkv_w     = (const float*)d_in[1];
  const float* qkv_b     = (const float*)d_in[2];
  const float* rel_table = (const float*)d_in[3];
  const float* n1w       = (const float*)d_in[4];
  const float* n1b       = (const float*)d_in[5];
  const float* n2w       = (const float*)d_in[6];
  const float* n2b       = (const float*)d_in[7];
  const float* proj_w    = (const float*)d_in[8];
  const float* proj_b    = (const float*)d_in[9];
  const float* fw        = (const float*)d_in[10];
  const float* fb        = (const float*)d_in[11];
  const float* w1        = (const float*)d_in[12];
  const float* b1        = (const float*)d_in[13];
  const float* w2        = (const float*)d_in[14];
  const float* b2        = (const float*)d_in[15];

  float* ws  = (float*)d_ws;
  float* q   = ws;                       // BL*32 floats
  float* k   = ws + 1048576;
  float* v   = ws + 2097152;
  float* y2  = ws + 3145728;             // BL*64 floats
  unsigned short* wctT = (unsigned short*)(ws + 5242880);  // 64*800 bf16
  float* bc  = ws + 5268480;             // 64 floats
  float* out = (float*)d_out;

  k_combine<<<201, 256, 0, stream>>>(proj_w, proj_b, fw, fb, wctT, bc);
  k_ln_qkv<<<128, 256, 0, stream>>>(x, qkv_w, qkv_b, n1w, n1b, q, k, v);
  k_attn<<<dim3(WW/TW, HH/TH, 2), 256, 0, stream>>>(q, k, v, rel_table, wctT, bc, y2);
  k_mlp<<<256, 128, 0, stream>>>(y2, n2w, n2b, w1, b1, w2, b2, out);
}

// Round 3
// 763.592 us; speedup vs baseline: 2.1878x; 2.1878x over previous
//
#include <hip/hip_runtime.h>
#include <cstdint>
#include <cstddef>

#define HH 128
#define WW 128
#define LL 16384   // HH*WW
#define BL 32768   // B*LL

typedef float  f32x4  __attribute__((ext_vector_type(4)));
typedef short  bf16x8 __attribute__((ext_vector_type(8)));
typedef unsigned short u16x8 __attribute__((ext_vector_type(8)));

static __device__ __forceinline__ unsigned short f2bf(float x) {
  union { float f; unsigned int u; } c; c.f = x;
  unsigned int r = (c.u + 0x7fffu + ((c.u >> 16) & 1u)) >> 16;   // RNE
  return (unsigned short)r;
}
static __device__ __forceinline__ float bflo(unsigned int u) {
  union { unsigned int u; float f; } c; c.u = u << 16; return c.f;
}
static __device__ __forceinline__ float bfhi(unsigned int u) {
  union { unsigned int u; float f; } c; c.u = u & 0xffff0000u; return c.f;
}

// ------------- k0: fold proj into fusion weight; emit B^T bf16 [64][800], kk = t*32+c -
__global__ __launch_bounds__(256) void k_combine(
    const float* __restrict__ proj_w, const float* __restrict__ proj_b,
    const float* __restrict__ fw, const float* __restrict__ fb,
    unsigned short* __restrict__ wctT, float* __restrict__ bc)
{
  if (blockIdx.x == 200) {
    int o = threadIdx.x;
    if (o < 64) {
      float acc = proj_b[o];
      for (int m = 0; m < 64; ++m) acc = fmaf(proj_w[o*64+m], fb[m], acc);
      bc[o] = acc;
    }
    return;
  }
  int gid = blockIdx.x * 256 + threadIdx.x;   // 0..51199 = o*800 + kk
  int o  = gid / 800;
  int kk = gid - o * 800;
  int c  = kk & 31;        // de-interleaved channel (nh*16+d)
  int t  = kk >> 5;        // window position 0..24
  int in = c * 25 + t;     // fusion weight flat index
  float acc = 0.f;
  for (int m = 0; m < 64; ++m) acc = fmaf(proj_w[o*64+m], fw[m*800+in], acc);
  wctT[gid] = f2bf(acc);
}

// ---------------- k1: LayerNorm + QKV, store q/k/v de-interleaved (c' = nh*16 + d) ----
__global__ __launch_bounds__(256) void k_ln_qkv(
    const float* __restrict__ x, const float* __restrict__ qkv_w,
    const float* __restrict__ qkv_b, const float* __restrict__ n1w,
    const float* __restrict__ n1b, float* __restrict__ qo,
    float* __restrict__ ko, float* __restrict__ vo)
{
  __shared__ float sW[96*32];
  __shared__ float sB[96];
  __shared__ float sNw[32], sNb[32];
  for (int i = threadIdx.x; i < 96*32; i += 256) sW[i] = qkv_w[i];
  if (threadIdx.x < 96) sB[threadIdx.x] = qkv_b[threadIdx.x];
  if (threadIdx.x < 32) { sNw[threadIdx.x] = n1w[threadIdx.x]; sNb[threadIdx.x] = n1b[threadIdx.x]; }
  __syncthreads();
  int gid = blockIdx.x * 256 + threadIdx.x;   // 0..BL-1
  int b = gid >> 14, l = gid & (LL - 1);
  const float* xp = x + (size_t)b * 32 * LL + l;
  float xv[32];
  float mean = 0.f;
  #pragma unroll
  for (int c = 0; c < 32; ++c) { xv[c] = xp[(size_t)c * LL]; mean += xv[c]; }
  mean *= 0.03125f;
  float var = 0.f;
  #pragma unroll
  for (int c = 0; c < 32; ++c) { float d = xv[c] - mean; var = fmaf(d, d, var); }
  float rs = rsqrtf(var * 0.03125f + 1e-5f);
  #pragma unroll
  for (int c = 0; c < 32; ++c) xv[c] = (xv[c] - mean) * rs * sNw[c] + sNb[c];
  size_t base = (size_t)gid * 32;
  float* outs[3] = {qo, ko, vo};
  #pragma unroll
  for (int p = 0; p < 3; ++p) {
    float* op = outs[p] + base;
    for (int o = 0; o < 32; ++o) {
      const float* wr = &sW[(p*32 + o) * 32];
      float acc = sB[p*32 + o];
      #pragma unroll
      for (int c = 0; c < 32; ++c) acc = fmaf(xv[c], wr[c], acc);
      op[(o & 1) * 16 + (o >> 1)] = acc;
    }
  }
}

// ---------------- k2: tiled windowed attention + fused (fusion∘proj) MFMA GEMM -------
// Block = 4x8 = 32 locations, 256 threads (4 waves).
#define TH 4
#define TW 8
#define HP 8     // TH+4
#define WP 12    // TW+4
#define NPOS 96  // HP*WP
#define PSTR 36  // fp32 halo row stride (floats)
#define VSTR 40  // bf16 V halo row stride (ushorts)
#define OSTRU 264 // sO row stride (ushorts): 256 kk + 8 pad

__global__ __launch_bounds__(256, 2) void k_attn(
    const float* __restrict__ qi, const float* __restrict__ ki,
    const float* __restrict__ vi, const float* __restrict__ rel_table,
    const unsigned short* __restrict__ wctT, const float* __restrict__ bc,
    float* __restrict__ y2)
{
  __shared__ __align__(16) float sQ[NPOS*PSTR];          // 13824 B
  __shared__ __align__(16) float sK[NPOS*PSTR];          // 13824 B
  __shared__ __align__(16) unsigned short sV[NPOS*VSTR]; // 7680 B
  __shared__ __align__(16) unsigned short sO[32*OSTRU];  // 16896 B
  __shared__ float sRT[162];
  __shared__ float sPar[NPOS];

  int tid = threadIdx.x;
  int lane = tid & 63, wv = tid >> 6;
  int b  = blockIdx.z;
  int h0 = blockIdx.y * TH, w0 = blockIdx.x * TW;

  for (int i = tid; i < 162; i += 256) sRT[i] = rel_table[i];
  // halo staging: Q,K fp32; V bf16; parity flags
  for (int idx = tid; idx < NPOS*8; idx += 256) {
    int pos = idx >> 3, c4 = idx & 7;
    int ph = pos / 12, pw = pos - ph * 12;
    int h2 = h0 + ph - 2, w2 = w0 + pw - 2;
    float4 qv = make_float4(0.f,0.f,0.f,0.f), kv = qv, vv = qv;
    bool valid = ((unsigned)h2 < HH) && ((unsigned)w2 < WW);
    if (valid) {
      size_t off = ((size_t)((b << 14) + (h2 << 7) + w2)) * 32 + c4 * 4;
      qv = *(const float4*)(qi + off);
      kv = *(const float4*)(ki + off);
      vv = *(const float4*)(vi + off);
    }
    *(float4*)&sQ[pos*PSTR + c4*4] = qv;
    *(float4*)&sK[pos*PSTR + c4*4] = kv;
    uint2 vp;
    vp.x = (unsigned int)f2bf(vv.x) | ((unsigned int)f2bf(vv.y) << 16);
    vp.y = (unsigned int)f2bf(vv.z) | ((unsigned int)f2bf(vv.w) << 16);
    *(uint2*)&sV[pos*VSTR + c4*4] = vp;
    if (c4 == 0) sPar[pos] = (valid && (((h2 + w2) & 1) == 1)) ? 1.f : 0.f;
  }
  __syncthreads();

  f32x4 acc[2] = {{0.f,0.f,0.f,0.f},{0.f,0.f,0.f,0.f}};
  int ocol = wv * 16 + (lane & 15);

  for (int it = 0; it < 4; ++it) {
    int rest = it * 8 + wv * 2 + (lane >> 5);   // half-wave uniform; halves share r
    if (rest < 26) {
      int nh = rest & 1, r = rest >> 1;         // r 0..12
      int loc = lane & 31;
      int ly = loc >> 3, lx = loc & 7;
      int posb = ly * 12 + lx;
      int nrr = (2*r + 1 < 25) ? 2 : 1;         // wave-uniform trip count
      for (int rr = 0; rr < nrr; ++rr) {
        int tq = 2*r + rr;
        int iq = tq / 5, jq = tq - iq * 5;
        int pq = posb + iq * 12 + jq;
        float parq = sPar[pq];
        float qa[16];
        {
          const float* p0 = &sQ[pq*PSTR + nh*16];
          #pragma unroll
          for (int e = 0; e < 4; ++e) {
            float4 t0 = *(const float4*)(p0 + e*4);
            qa[4*e]=t0.x; qa[4*e+1]=t0.y; qa[4*e+2]=t0.z; qa[4*e+3]=t0.w;
          }
        }
        float s[25];
        float mx = -1e30f;
        #pragma unroll
        for (int tk = 0; tk < 25; ++tk) {
          const int ik = tk / 5, jk = tk % 5;   // compile-time
          int pk = posb + ik * 12 + jk;
          const float* kp = &sK[pk*PSTR + nh*16];
          float a0 = 0.f;
          #pragma unroll
          for (int e = 0; e < 4; ++e) {
            float4 k4 = *(const float4*)(kp + e*4);
            a0 = fmaf(qa[4*e],k4.x,a0); a0 = fmaf(qa[4*e+1],k4.y,a0);
            a0 = fmaf(qa[4*e+2],k4.z,a0); a0 = fmaf(qa[4*e+3],k4.w,a0);
          }
          float park = sPar[pk];
          float bias = sRT[((iq-ik+4)*9 + (jq-jk+4))*2 + nh];
          float msk = (parq*park == 1.f) ? 0.f : -100.f;
          s[tk] = fmaf(a0, 0.25f, bias) + msk;
          mx = fmaxf(mx, s[tk]);
        }
        float sum = 0.f;
        #pragma unroll
        for (int tk = 0; tk < 25; ++tk) { float e0 = __expf(s[tk]-mx); s[tk] = e0; sum += e0; }
        float inv = 1.f / sum;
        #pragma unroll
        for (int tk = 0; tk < 25; ++tk) s[tk] *= inv;
        // PV (V in bf16, bit-expand)
        float o0[16];
        #pragma unroll
        for (int d = 0; d < 16; ++d) o0[d] = 0.f;
        #pragma unroll
        for (int tk = 0; tk < 25; ++tk) {
          const int ik = tk / 5, jk = tk % 5;
          int pk = posb + ik * 12 + jk;
          const unsigned short* vp = &sV[pk*VSTR + nh*16];
          uint4 va = *(const uint4*)(vp);
          uint4 vb = *(const uint4*)(vp + 8);
          float p0 = s[tk];
          unsigned int uu[8] = {va.x, va.y, va.z, va.w, vb.x, vb.y, vb.z, vb.w};
          #pragma unroll
          for (int u = 0; u < 8; ++u) {
            o0[2*u]   = fmaf(p0, bflo(uu[u]), o0[2*u]);
            o0[2*u+1] = fmaf(p0, bfhi(uu[u]), o0[2*u+1]);
          }
        }
        // write O row to sO (bf16), kk_local = (tq - it*8)*32 + nh*16
        int kl0 = (tq - it*8) * 32 + nh * 16;
        u16x8 w0v, w1v;
        #pragma unroll
        for (int j = 0; j < 8; ++j) { w0v[j] = f2bf(o0[j]); w1v[j] = f2bf(o0[8+j]); }
        *(u16x8*)&sO[loc*OSTRU + kl0] = w0v;
        *(u16x8*)&sO[loc*OSTRU + kl0 + 8] = w1v;
      }
    }
    __syncthreads();
    // MFMA phase: K-chunk [it*256, it*256 + nk*32)
    int nk = (it < 3) ? 8 : 1;
    const unsigned short* bcol = wctT + (size_t)ocol * 800 + it * 256 + (lane >> 4) * 8;
    for (int kt = 0; kt < nk; ++kt) {
      bf16x8 bfrag = *(const bf16x8*)(bcol + kt * 32);
      #pragma unroll
      for (int mt = 0; mt < 2; ++mt) {
        bf16x8 afrag = *(const bf16x8*)&sO[(mt*16 + (lane & 15))*OSTRU + kt*32 + (lane >> 4)*8];
        acc[mt] = __builtin_amdgcn_mfma_f32_16x16x32_bf16(afrag, bfrag, acc[mt], 0, 0, 0);
      }
    }
    __syncthreads();
  }
  // epilogue: y2[loc][o] = acc + bc[o]
  float bco = bc[ocol];
  #pragma unroll
  for (int mt = 0; mt < 2; ++mt) {
    #pragma unroll
    for (int r2 = 0; r2 < 4; ++r2) {
      int loc = mt * 16 + (lane >> 4) * 4 + r2;
      int ly = loc >> 3, lx = loc & 7;
      int gid = (b << 14) + ((h0 + ly) << 7) + (w0 + lx);
      y2[(size_t)gid * 64 + ocol] = acc[mt][r2] + bco;
    }
  }
}

// ---------------- k3: LN + MLP(GELU exact) + residual + transpose store --------------
__global__ __launch_bounds__(128, 1) void k_mlp(
    const float* __restrict__ y2, const float* __restrict__ n2w,
    const float* __restrict__ n2b, const float* __restrict__ w1,
    const float* __restrict__ b1, const float* __restrict__ w2,
    const float* __restrict__ b2, float* __restrict__ out)
{
  __shared__ __align__(16) float sW1[128*64];
  __shared__ __align__(16) float sW2[64*128];
  __shared__ float sNw[64], sNb[64], sB1[128], sB2[64];
  int tid = threadIdx.x;
  for (int i = tid; i < 128*64; i += 128) sW1[i] = w1[i];
  for (int i = tid; i < 64*128; i += 128) sW2[i] = w2[i];
  if (tid < 64) { sNw[tid] = n2w[tid]; sNb[tid] = n2b[tid]; sB2[tid] = b2[tid]; }
  sB1[tid] = b1[tid];
  __syncthreads();
  int gid = blockIdx.x * 128 + tid;
  int b = gid >> 14, l = gid & (LL - 1);
  float yv[64], hn[64], macc[64];
  const float* yp = y2 + (size_t)gid * 64;
  float mean = 0.f;
  #pragma unroll
  for (int c = 0; c < 64; ++c) { yv[c] = yp[c]; mean += yv[c]; }
  mean *= (1.f/64.f);
  float var = 0.f;
  #pragma unroll
  for (int c = 0; c < 64; ++c) { float d = yv[c] - mean; var = fmaf(d, d, var); }
  float rs = rsqrtf(var * (1.f/64.f) + 1e-5f);
  #pragma unroll
  for (int c = 0; c < 64; ++c) hn[c] = (yv[c] - mean) * rs * sNw[c] + sNb[c];
  #pragma unroll
  for (int o = 0; o < 64; ++o) macc[o] = sB2[o];
  for (int j4 = 0; j4 < 32; ++j4) {
    float g[4];
    #pragma unroll
    for (int u = 0; u < 4; ++u) {
      int j = j4*4 + u;
      const float* wr = &sW1[j*64];
      float hj = sB1[j];
      #pragma unroll
      for (int c = 0; c < 64; ++c) hj = fmaf(hn[c], wr[c], hj);
      g[u] = 0.5f * hj * (1.f + erff(hj * 0.70710678118f));
    }
    #pragma unroll
    for (int o = 0; o < 64; ++o) {
      const float4 w4 = *(const float4*)(&sW2[o*128 + j4*4]);
      macc[o] = fmaf(g[0], w4.x, fmaf(g[1], w4.y, fmaf(g[2], w4.z, fmaf(g[3], w4.w, macc[o]))));
    }
  }
  size_t ob = (size_t)b * 64 * LL + l;
  #pragma unroll
  for (int o = 0; o < 64; ++o) out[ob + (size_t)o * LL] = yv[o] + macc[o];
}

extern "C" void kernel_launch(void* const* d_in, const int* in_sizes, int n_in,
                              void* d_out, int out_size, void* d_ws, size_t ws_size,
                              hipStream_t stream) {
  const float* x         = (const float*)d_in[0];
  const float* qkv_w     = (const float*)d_in[1];
  const float* qkv_b     = (const float*)d_in[2];
  const float* rel_table = (const float*)d_in[3];
  const float* n1w       = (const float*)d_in[4];
  const float* n1b       = (const float*)d_in[5];
  const float* n2w       = (const float*)d_in[6];
  const float* n2b       = (const float*)d_in[7];
  const float* proj_w    = (const float*)d_in[8];
  const float* proj_b    = (const float*)d_in[9];
  const float* fw        = (const float*)d_in[10];
  const float* fb        = (const float*)d_in[11];
  const float* w1        = (const float*)d_in[12];
  const float* b1        = (const float*)d_in[13];
  const float* w2        = (const float*)d_in[14];
  const float* b2        = (const float*)d_in[15];

  float* ws  = (float*)d_ws;
  float* q   = ws;                       // BL*32 floats
  float* k   = ws + 1048576;
  float* v   = ws + 2097152;
  float* y2  = ws + 3145728;             // BL*64 floats
  unsigned short* wctT = (unsigned short*)(ws + 5242880);  // 64*800 bf16
  float* bc  = ws + 5268480;             // 64 floats
  float* out = (float*)d_out;

  k_combine<<<201, 256, 0, stream>>>(proj_w, proj_b, fw, fb, wctT, bc);
  k_ln_qkv<<<128, 256, 0, stream>>>(x, qkv_w, qkv_b, n1w, n1b, q, k, v);
  k_attn<<<dim3(WW/TW, HH/TH, 2), 256, 0, stream>>>(q, k, v, rel_table, wctT, bc, y2);
  k_mlp<<<256, 128, 0, stream>>>(y2, n2w, n2b, w1, b1, w2, b2, out);
}